// Round 3
// baseline (1213.359 us; speedup 1.0000x reference)
//
#include <hip/hip_runtime.h>
#include <hip/hip_cooperative_groups.h>

namespace cg = cooperative_groups;

#define N_NODES   50000
#define N_EDGES   640000
#define DIM       128
#define N_LAYERS  5
#define N_GRAPHS  512
#define N_CLASSES 128
#define NB_SCAN   196   // ceil(N_NODES/256)
#define NT        ((N_NODES + 63) / 64)   // 782 row-tiles of 64

typedef __attribute__((ext_vector_type(8))) short short8;     // 8 bf16 (4 VGPRs)
typedef __attribute__((ext_vector_type(4))) float floatx4;    // MFMA acc

__device__ inline float bfhi(unsigned u) { return __uint_as_float(u & 0xffff0000u); }
__device__ inline float bflo(unsigned u) { return __uint_as_float(u << 16); }
__device__ inline unsigned f2bf(float f) {          // round-to-nearest-even
  unsigned x = __float_as_uint(f);
  return (x + 0x7fffu + ((x >> 16) & 1u)) >> 16;
}

// ---------------- zero-init scratch accumulators (ws is poisoned 0xAA) -----
__global__ void k_zero(int* __restrict__ deg, int* __restrict__ fill,
                       float* __restrict__ pool, float* __restrict__ cnt) {
  int i = blockIdx.x * 256 + threadIdx.x;
  if (i < N_NODES) { deg[i] = 0; fill[i] = 0; }
  if (i < N_GRAPHS * DIM) pool[i] = 0.f;
  if (i < N_GRAPHS) cnt[i] = 0.f;
}

// ---------------- degree histogram over dst --------------------------------
__global__ void k_deg(const int* __restrict__ dst, int* __restrict__ deg) {
  int e = blockIdx.x * 256 + threadIdx.x;
  if (e < N_EDGES) atomicAdd(&deg[dst[e]], 1);
}

// ---------------- exclusive scan deg -> row_ptr (3 phases) -----------------
__global__ void k_scan1(const int* __restrict__ deg, int* __restrict__ bsum) {
  __shared__ int s[256];
  int t = threadIdx.x, i = blockIdx.x * 256 + t;
  s[t] = (i < N_NODES) ? deg[i] : 0;
  __syncthreads();
  for (int o = 128; o > 0; o >>= 1) {
    if (t < o) s[t] += s[t + o];
    __syncthreads();
  }
  if (t == 0) bsum[blockIdx.x] = s[0];
}

__global__ void k_scan2(int* __restrict__ bsum) {
  __shared__ int s[256];
  int t = threadIdx.x;
  s[t] = (t < NB_SCAN) ? bsum[t] : 0;
  __syncthreads();
  for (int o = 1; o < 256; o <<= 1) {
    int add = (t >= o) ? s[t - o] : 0;
    __syncthreads();
    s[t] += add;
    __syncthreads();
  }
  int ex = (t == 0) ? 0 : s[t - 1];
  if (t < NB_SCAN) bsum[t] = ex;
}

__global__ void k_scan3(const int* __restrict__ deg, const int* __restrict__ bsum,
                        int* __restrict__ row_ptr) {
  __shared__ int s[256];
  int t = threadIdx.x, i = blockIdx.x * 256 + t;
  s[t] = (i < N_NODES) ? deg[i] : 0;
  __syncthreads();
  for (int o = 1; o < 256; o <<= 1) {
    int add = (t >= o) ? s[t - o] : 0;
    __syncthreads();
    s[t] += add;
    __syncthreads();
  }
  int ex = bsum[blockIdx.x] + ((t == 0) ? 0 : s[t - 1]);
  if (i < N_NODES) row_ptr[i] = ex;
  if (blockIdx.x == 0 && t == 0) row_ptr[N_NODES] = N_EDGES;
}

// ---------------- CSR fill: one 8B scatter per edge (src,eid packed) -------
__global__ void k_fill(const int* __restrict__ src, const int* __restrict__ dst,
                       const int* __restrict__ row_ptr, int* __restrict__ fill,
                       int2* __restrict__ col) {
  int e = blockIdx.x * 256 + threadIdx.x;
  if (e < N_EDGES) {
    int d = dst[e];
    int pos = row_ptr[d] + atomicAdd(&fill[d], 1);
    col[pos] = make_int2(src[e], e);
  }
}

// ------- weights: bf16 + transpose:  Wt[l][c][k] = W[l][k][c] --------------
__global__ void k_wconv(const float* __restrict__ Ws, const float* __restrict__ Wes,
                        unsigned short* __restrict__ Wt_s, unsigned short* __restrict__ Wt_e) {
  int idx = blockIdx.x * 256 + threadIdx.x;          // total 2*5*128*128 = 163840
  int which = idx / (N_LAYERS * DIM * DIM);
  int rem = idx - which * (N_LAYERS * DIM * DIM);
  int l = rem >> 14;            // /16384
  int c = (rem >> 7) & 127;
  int k = rem & 127;
  const float* W = which ? Wes : Ws;
  unsigned short* O = which ? Wt_e : Wt_s;
  float v = W[((size_t)l * DIM + k) * DIM + c];
  O[((size_t)l * DIM + c) * DIM + k] = (unsigned short)f2bf(v);
}

// ------- v0 = emb @ Ws[0]  (layer-0 rank-1 collapse: h0 rows are all emb) --
__global__ void k_v0(const float* __restrict__ node_emb, const float* __restrict__ Ws0,
                     float* __restrict__ v0) {
  int c = threadIdx.x;                 // 128 threads, 1 block
  float acc = 0.f;
  for (int k = 0; k < DIM; k++) acc += node_emb[k] * Ws0[(size_t)k * DIM + c];
  v0[c] = acc;
}

// -------- EAn = segsum(edge_attr,dst)/max(deg,1) (bf16); rdeg --------------
__global__ void k_ean_init(const int* __restrict__ row_ptr, const int2* __restrict__ col,
                           const float* __restrict__ edge_attr,
                           unsigned short* __restrict__ ean, float* __restrict__ rdeg) {
  int sub = threadIdx.x >> 5;
  int lane = threadIdx.x & 31;
  int i = blockIdx.x * 8 + sub;
  if (i >= N_NODES) return;
  int b = row_ptr[i], e = row_ptr[i + 1];
  float ax = 0.f, ay = 0.f, az = 0.f, aw = 0.f;
  int p = b;
  for (; p + 2 <= e; p += 2) {
    int e0 = col[p].y, e1 = col[p + 1].y;
    float4 v0 = ((const float4*)(edge_attr + (size_t)e0 * DIM))[lane];
    float4 v1 = ((const float4*)(edge_attr + (size_t)e1 * DIM))[lane];
    ax += v0.x + v1.x; ay += v0.y + v1.y; az += v0.z + v1.z; aw += v0.w + v1.w;
  }
  if (p < e) {
    int e0 = col[p].y;
    float4 v0 = ((const float4*)(edge_attr + (size_t)e0 * DIM))[lane];
    ax += v0.x; ay += v0.y; az += v0.z; aw += v0.w;
  }
  float r = 1.0f / (float)max(e - b, 1);
  if (lane == 0) rdeg[i] = r;
  uint2 o;
  o.x = f2bf(ax * r) | (f2bf(ay * r) << 16);
  o.y = f2bf(az * r) | (f2bf(aw * r) << 16);
  ((uint2*)(ean + (size_t)i * DIM))[lane] = o;
}

// ------- ALL layers fused in one cooperative kernel ------------------------
// layer 0:   h = relu(ean @ We0 + (1+[deg>0])*v0 + b0)          (rank-1 collapse)
// layer 1-4: h' = maybe_relu(u @ Ws_l + ean @ We_l + b_l),
//            u = hin + (A hin)/max(deg,1), gathered block-locally into LDS.
// grid.sync() between layers replaces 4 kernel-launch drains.
#define ACC8(v) { a0 += bflo(v.x); a1 += bfhi(v.x); a2 += bflo(v.y); a3 += bfhi(v.y); \
                  a4 += bflo(v.z); a5 += bfhi(v.z); a6 += bflo(v.w); a7 += bfhi(v.w); }

__global__ __launch_bounds__(256) void k_layers(
    const int* __restrict__ row_ptr, const int2* __restrict__ col,
    const float* __restrict__ rdeg, const unsigned short* __restrict__ ean,
    const unsigned short* __restrict__ Wt_s, const unsigned short* __restrict__ Wt_e,
    const float* __restrict__ bs, const float* __restrict__ v0,
    const int* __restrict__ deg, unsigned short* __restrict__ hA,
    unsigned short* __restrict__ hB) {
  cg::grid_group gg = cg::this_grid();
  __shared__ unsigned short sU[64][136];   // gathered u rows, full K=128 (+8 pad)
  __shared__ unsigned short sE[64][136];   // ean rows, full K=128
  __shared__ unsigned short sW[128][72];   // W chunk staging (64-k at a time)
  int tid = threadIdx.x;
  int wave = tid >> 6, lane = tid & 63;
  int quad = lane >> 4, l16 = lane & 15;

  const unsigned short* hin = hA;
  unsigned short* hout = hA;               // layer 0 writes hA

  for (int l = 0; l < N_LAYERS; l++) {
    const unsigned short* W0 = Wt_s + (size_t)l * DIM * DIM;
    const unsigned short* W1 = Wt_e + (size_t)l * DIM * DIM;
    const float* bias = bs + (size_t)l * DIM;
    int relu = (l < N_LAYERS - 1);

    for (int tile = blockIdx.x; tile < NT; tile += gridDim.x) {
      int row0 = tile * 64;
      __syncthreads();   // protect LDS reuse across tile iterations

      // ---- stage ean rows full-width: 1024 uint4, 4 per thread
      #pragma unroll
      for (int q = 0; q < 4; q++) {
        int s = tid + 256 * q;
        int r = s >> 4, seg = s & 15;
        int grow = row0 + r;
        uint4 v = make_uint4(0u, 0u, 0u, 0u);
        if (grow < N_NODES) v = *(const uint4*)(ean + (size_t)grow * DIM + seg * 8);
        *(uint4*)(&sE[r][seg * 8]) = v;
      }

      // ---- gather u rows into sU (layers 1..4 only)
      if (l > 0) {
        int g = tid >> 4, glane = tid & 15;
        for (int n = 0; n < 4; n++) {
          int r = g + n * 16;
          int i = row0 + r;
          if (i < N_NODES) {
            int b = row_ptr[i], e = row_ptr[i + 1];
            float a0 = 0.f, a1 = 0.f, a2 = 0.f, a3 = 0.f,
                  a4 = 0.f, a5 = 0.f, a6 = 0.f, a7 = 0.f;
            int p = b;
            for (; p + 4 <= e; p += 4) {
              int j0 = col[p].x, j1 = col[p + 1].x, j2 = col[p + 2].x, j3 = col[p + 3].x;
              uint4 w0 = *(const uint4*)(hin + (size_t)j0 * DIM + glane * 8);
              uint4 w1 = *(const uint4*)(hin + (size_t)j1 * DIM + glane * 8);
              uint4 w2 = *(const uint4*)(hin + (size_t)j2 * DIM + glane * 8);
              uint4 w3 = *(const uint4*)(hin + (size_t)j3 * DIM + glane * 8);
              ACC8(w0); ACC8(w1); ACC8(w2); ACC8(w3);
            }
            for (; p < e; p++) {
              int j0 = col[p].x;
              uint4 w0 = *(const uint4*)(hin + (size_t)j0 * DIM + glane * 8);
              ACC8(w0);
            }
            float rr = rdeg[i];
            uint4 hv = *(const uint4*)(hin + (size_t)i * DIM + glane * 8);
            uint4 o;
            o.x = f2bf(bflo(hv.x) + a0 * rr) | (f2bf(bfhi(hv.x) + a1 * rr) << 16);
            o.y = f2bf(bflo(hv.y) + a2 * rr) | (f2bf(bfhi(hv.y) + a3 * rr) << 16);
            o.z = f2bf(bflo(hv.z) + a4 * rr) | (f2bf(bfhi(hv.z) + a5 * rr) << 16);
            o.w = f2bf(bflo(hv.w) + a6 * rr) | (f2bf(bfhi(hv.w) + a7 * rr) << 16);
            *(uint4*)(&sU[r][glane * 8]) = o;
          } else {
            *(uint4*)(&sU[r][glane * 8]) = make_uint4(0u, 0u, 0u, 0u);
          }
        }
      }

      // ---- GEMM: acc = (l>0 ? sU @ W0 : 0) + sE @ W1
      floatx4 acc[8];
      #pragma unroll
      for (int ci = 0; ci < 8; ci++) acc[ci] = (floatx4){0.f, 0.f, 0.f, 0.f};

      int mstart = (l == 0) ? 1 : 0;
      for (int m = mstart; m < 2; m++) {
        const unsigned short* W = m ? W1 : W0;
        const unsigned short (*sA)[136] = m ? sE : sU;
        for (int kc = 0; kc < 128; kc += 64) {
          __syncthreads();   // orders sU/sE/sW writes before MFMA reads
          #pragma unroll
          for (int q = 0; q < 4; q++) {
            int s = tid + 256 * q;
            int r = s >> 3, seg = s & 7;
            *(uint4*)(&sW[r][seg * 8]) =
                *(const uint4*)(W + (size_t)r * DIM + kc + seg * 8);
          }
          __syncthreads();
          #pragma unroll
          for (int ks = 0; ks < 64; ks += 32) {
            short8 a = *(const short8*)(&sA[wave * 16 + l16][kc + ks + quad * 8]);
            #pragma unroll
            for (int ci = 0; ci < 8; ci++) {
              short8 b = *(const short8*)(&sW[ci * 16 + l16][ks + quad * 8]);
              acc[ci] = __builtin_amdgcn_mfma_f32_16x16x32_bf16(a, b, acc[ci], 0, 0, 0);
            }
          }
        }
      }

      // ---- epilogue: row = row0 + wave*16 + quad*4 + r ; col = ci*16 + l16
      #pragma unroll
      for (int ci = 0; ci < 8; ci++) {
        int col_ = ci * 16 + l16;
        float bv = bias[col_];
        float vv = (l == 0) ? v0[col_] : 0.f;
        #pragma unroll
        for (int r = 0; r < 4; r++) {
          int row = row0 + wave * 16 + quad * 4 + r;
          if (row < N_NODES) {
            float v = acc[ci][r] + bv;
            if (l == 0) v += ((deg[row] > 0) ? 2.f : 1.f) * vv;
            if (relu) v = fmaxf(v, 0.f);
            hout[(size_t)row * DIM + col_] = (unsigned short)f2bf(v);
          }
        }
      }
    }

    if (l < N_LAYERS - 1) gg.sync();   // layer boundary

    if (l == 0) { hin = hA; hout = hB; }
    else { const unsigned short* t = hin; hin = hout; hout = (unsigned short*)t; }
  }
  // ping-pong parity: L0->hA, L1 hA->hB, L2 hB->hA, L3 hA->hB, L4 hB->hA.
  // Final result is in hA.
}

// ---------------- mean-pool per graph (batch sorted: run-length) -----------
__global__ void k_pool(const unsigned short* __restrict__ h, const int* __restrict__ batch,
                       float* __restrict__ pool, float* __restrict__ cnt) {
  int t = threadIdx.x;                 // column 0..127
  int i0 = blockIdx.x * 128;
  int iend = min(i0 + 128, N_NODES);
  float acc = 0.f;
  int cur = -1, run = 0;
  for (int i = i0; i < iend; i++) {
    int g = batch[i];
    if (g != cur) {
      if (cur >= 0) {
        atomicAdd(&pool[(size_t)cur * DIM + t], acc);
        if (t == 0) atomicAdd(&cnt[cur], (float)run);
      }
      acc = 0.f; run = 0; cur = g;
    }
    acc += __uint_as_float(((unsigned)h[(size_t)i * DIM + t]) << 16);
    run++;
  }
  if (cur >= 0) {
    atomicAdd(&pool[(size_t)cur * DIM + t], acc);
    if (t == 0) atomicAdd(&cnt[cur], (float)run);
  }
}

// ---------------- out = (pool/cnt) @ Wp + bp -------------------------------
__global__ void k_out(const float* __restrict__ pool, const float* __restrict__ cnt,
                      const float* __restrict__ Wp, const float* __restrict__ bp,
                      float* __restrict__ out) {
  __shared__ float sp[DIM];
  int g = blockIdx.x, t = threadIdx.x;
  sp[t] = pool[(size_t)g * DIM + t];
  __syncthreads();
  float r = 1.0f / fmaxf(cnt[g], 1.0f);
  float acc = 0.f;
  for (int k = 0; k < DIM; k++) acc += sp[k] * Wp[(size_t)k * N_CLASSES + t];
  out[(size_t)g * N_CLASSES + t] = acc * r + bp[t];
}

extern "C" void kernel_launch(void* const* d_in, const int* in_sizes, int n_in,
                              void* d_out, int out_size, void* d_ws, size_t ws_size,
                              hipStream_t stream) {
  (void)in_sizes; (void)n_in; (void)out_size; (void)ws_size;
  const int*   x          = (const int*)d_in[0];
  const int*   edge_index = (const int*)d_in[1];
  const float* edge_attr  = (const float*)d_in[2];
  const int*   batch      = (const int*)d_in[3];
  const float* node_emb   = (const float*)d_in[4];
  const float* Ws         = (const float*)d_in[5];
  const float* bsin       = (const float*)d_in[6];
  const float* Wes        = (const float*)d_in[7];
  const float* Wp         = (const float*)d_in[8];
  const float* bp         = (const float*)d_in[9];
  (void)x;
  float* out = (float*)d_out;
  const int* src = edge_index;
  const int* dst = edge_index + N_EDGES;

  char* p = (char*)d_ws;
  auto alloc = [&](size_t bytes) {
    void* q = (void*)p;
    p += (bytes + 255) & ~(size_t)255;
    return q;
  };
  unsigned short* h    = (unsigned short*)alloc((size_t)N_NODES * DIM * 2);
  unsigned short* h2   = (unsigned short*)alloc((size_t)N_NODES * DIM * 2);
  unsigned short* ean  = (unsigned short*)alloc((size_t)N_NODES * DIM * 2);
  unsigned short* Wt_s = (unsigned short*)alloc((size_t)N_LAYERS * DIM * DIM * 2);
  unsigned short* Wt_e = (unsigned short*)alloc((size_t)N_LAYERS * DIM * DIM * 2);
  int*   deg     = (int*)  alloc((size_t)N_NODES * 4);
  float* rdeg    = (float*)alloc((size_t)N_NODES * 4);
  int*   row_ptr = (int*)  alloc((size_t)(N_NODES + 64) * 4);
  int*   fill    = (int*)  alloc((size_t)N_NODES * 4);
  int2*  col     = (int2*) alloc((size_t)N_EDGES * 8);
  float* pool    = (float*)alloc((size_t)N_GRAPHS * DIM * 4);
  float* cnt     = (float*)alloc((size_t)N_GRAPHS * 4);
  int*   bsum    = (int*)  alloc(256 * 4);
  float* v0      = (float*)alloc(DIM * 4);

  k_zero<<<256, 256, 0, stream>>>(deg, fill, pool, cnt);
  k_deg<<<(N_EDGES + 255) / 256, 256, 0, stream>>>(dst, deg);
  k_scan1<<<NB_SCAN, 256, 0, stream>>>(deg, bsum);
  k_scan2<<<1, 256, 0, stream>>>(bsum);
  k_scan3<<<NB_SCAN, 256, 0, stream>>>(deg, bsum, row_ptr);
  k_fill<<<(N_EDGES + 255) / 256, 256, 0, stream>>>(src, dst, row_ptr, fill, col);
  k_wconv<<<(2 * N_LAYERS * DIM * DIM) / 256, 256, 0, stream>>>(Ws, Wes, Wt_s, Wt_e);
  k_v0<<<1, DIM, 0, stream>>>(node_emb, Ws, v0);
  k_ean_init<<<(N_NODES + 7) / 8, 256, 0, stream>>>(row_ptr, col, edge_attr, ean, rdeg);

  // ---- all 5 layers in one cooperative kernel (grid sized to co-residency)
  {
    int maxb = 0;
    hipError_t oe = hipOccupancyMaxActiveBlocksPerMultiprocessor(&maxb, k_layers, 256, 0);
    if (oe != hipSuccess || maxb < 1) maxb = 1;
    int grid = maxb * 256;            // 256 CUs
    if (grid > NT) grid = NT;
    const int*            a_row_ptr = row_ptr;
    const int2*           a_col     = col;
    const float*          a_rdeg    = rdeg;
    const unsigned short* a_ean     = ean;
    const unsigned short* a_Wt_s    = Wt_s;
    const unsigned short* a_Wt_e    = Wt_e;
    const float*          a_bs      = bsin;
    const float*          a_v0      = v0;
    const int*            a_deg     = deg;
    unsigned short*       a_hA      = h;
    unsigned short*       a_hB      = h2;
    void* args[] = {&a_row_ptr, &a_col, &a_rdeg, &a_ean, &a_Wt_s, &a_Wt_e,
                    &a_bs, &a_v0, &a_deg, &a_hA, &a_hB};
    hipLaunchCooperativeKernel((void*)k_layers, dim3(grid), dim3(256),
                               args, 0, stream);
  }

  // final h is in buffer `h` (see parity note in k_layers)
  k_pool<<<(N_NODES + 127) / 128, 128, 0, stream>>>(h, batch, pool, cnt);
  k_out<<<N_GRAPHS, N_CLASSES, 0, stream>>>(pool, cnt, Wp, bp, out);
}

// Round 4
// 757.993 us; speedup vs baseline: 1.6008x; 1.6008x over previous
//
#include <hip/hip_runtime.h>

#define N_NODES   50000
#define N_EDGES   640000
#define DIM       128
#define N_LAYERS  5
#define N_GRAPHS  512
#define N_CLASSES 128
#define NB_SCAN   196   // ceil(N_NODES/256)

typedef __attribute__((ext_vector_type(8))) short short8;     // 8 bf16 (4 VGPRs)
typedef __attribute__((ext_vector_type(4))) float floatx4;    // MFMA acc

__device__ inline float bfhi(unsigned u) { return __uint_as_float(u & 0xffff0000u); }
__device__ inline float bflo(unsigned u) { return __uint_as_float(u << 16); }
__device__ inline unsigned f2bf(float f) {          // round-to-nearest-even
  unsigned x = __float_as_uint(f);
  return (x + 0x7fffu + ((x >> 16) & 1u)) >> 16;
}

// ---------------- zero-init scratch accumulators (ws is poisoned 0xAA) -----
__global__ void k_zero(int* __restrict__ deg, int* __restrict__ fill,
                       float* __restrict__ pool, float* __restrict__ cnt) {
  int i = blockIdx.x * 256 + threadIdx.x;
  if (i < N_NODES) { deg[i] = 0; fill[i] = 0; }
  if (i < N_GRAPHS * DIM) pool[i] = 0.f;
  if (i < N_GRAPHS) cnt[i] = 0.f;
}

// ---------------- degree histogram over dst --------------------------------
__global__ void k_deg(const int* __restrict__ dst, int* __restrict__ deg) {
  int e = blockIdx.x * 256 + threadIdx.x;
  if (e < N_EDGES) atomicAdd(&deg[dst[e]], 1);
}

// ---------------- exclusive scan deg -> row_ptr (3 phases) -----------------
__global__ void k_scan1(const int* __restrict__ deg, int* __restrict__ bsum) {
  __shared__ int s[256];
  int t = threadIdx.x, i = blockIdx.x * 256 + t;
  s[t] = (i < N_NODES) ? deg[i] : 0;
  __syncthreads();
  for (int o = 128; o > 0; o >>= 1) {
    if (t < o) s[t] += s[t + o];
    __syncthreads();
  }
  if (t == 0) bsum[blockIdx.x] = s[0];
}

__global__ void k_scan2(int* __restrict__ bsum) {
  __shared__ int s[256];
  int t = threadIdx.x;
  s[t] = (t < NB_SCAN) ? bsum[t] : 0;
  __syncthreads();
  for (int o = 1; o < 256; o <<= 1) {
    int add = (t >= o) ? s[t - o] : 0;
    __syncthreads();
    s[t] += add;
    __syncthreads();
  }
  int ex = (t == 0) ? 0 : s[t - 1];
  if (t < NB_SCAN) bsum[t] = ex;
}

__global__ void k_scan3(const int* __restrict__ deg, const int* __restrict__ bsum,
                        int* __restrict__ row_ptr) {
  __shared__ int s[256];
  int t = threadIdx.x, i = blockIdx.x * 256 + t;
  s[t] = (i < N_NODES) ? deg[i] : 0;
  __syncthreads();
  for (int o = 1; o < 256; o <<= 1) {
    int add = (t >= o) ? s[t - o] : 0;
    __syncthreads();
    s[t] += add;
    __syncthreads();
  }
  int ex = bsum[blockIdx.x] + ((t == 0) ? 0 : s[t - 1]);
  if (i < N_NODES) row_ptr[i] = ex;
  if (blockIdx.x == 0 && t == 0) row_ptr[N_NODES] = N_EDGES;
}

// ---------------- CSR fill: one 8B scatter per edge (src,eid packed) -------
__global__ void k_fill(const int* __restrict__ src, const int* __restrict__ dst,
                       const int* __restrict__ row_ptr, int* __restrict__ fill,
                       int2* __restrict__ col) {
  int e = blockIdx.x * 256 + threadIdx.x;
  if (e < N_EDGES) {
    int d = dst[e];
    int pos = row_ptr[d] + atomicAdd(&fill[d], 1);
    col[pos] = make_int2(src[e], e);
  }
}

// ------- weights: bf16 + transpose:  Wt[l][c][k] = W[l][k][c] --------------
__global__ void k_wconv(const float* __restrict__ Ws, const float* __restrict__ Wes,
                        unsigned short* __restrict__ Wt_s, unsigned short* __restrict__ Wt_e) {
  int idx = blockIdx.x * 256 + threadIdx.x;          // total 2*5*128*128 = 163840
  int which = idx / (N_LAYERS * DIM * DIM);
  int rem = idx - which * (N_LAYERS * DIM * DIM);
  int l = rem >> 14;            // /16384
  int c = (rem >> 7) & 127;
  int k = rem & 127;
  const float* W = which ? Wes : Ws;
  unsigned short* O = which ? Wt_e : Wt_s;
  float v = W[((size_t)l * DIM + k) * DIM + c];
  O[((size_t)l * DIM + c) * DIM + k] = (unsigned short)f2bf(v);
}

// ------- v0 = emb @ Ws[0]  (layer-0 rank-1 collapse: h0 rows are all emb) --
// Valid because x==0 for every node (vocab=1 embedding), so h0 is rank-1 and
// (A h0)/max(deg,1) = emb exactly for deg>0 rows, 0 for deg==0 rows.
__global__ void k_v0(const float* __restrict__ node_emb, const float* __restrict__ Ws0,
                     float* __restrict__ v0) {
  int c = threadIdx.x;                 // 128 threads, 1 block
  float acc = 0.f;
  for (int k = 0; k < DIM; k++) acc += node_emb[k] * Ws0[(size_t)k * DIM + c];
  v0[c] = acc;
}

// -------- EAn = segsum(edge_attr,dst)/max(deg,1) (bf16); rdeg --------------
// 32 lanes per node (float4 -> full 512B row per wave-instr), 8 nodes/block.
// 4-deep unroll: 4 independent HBM row fetches in flight per node.
__global__ void k_ean_init(const int* __restrict__ row_ptr, const int2* __restrict__ col,
                           const float* __restrict__ edge_attr,
                           unsigned short* __restrict__ ean, float* __restrict__ rdeg) {
  int sub = threadIdx.x >> 5;
  int lane = threadIdx.x & 31;
  int i = blockIdx.x * 8 + sub;
  if (i >= N_NODES) return;
  int b = row_ptr[i], e = row_ptr[i + 1];
  float ax = 0.f, ay = 0.f, az = 0.f, aw = 0.f;
  int p = b;
  for (; p + 4 <= e; p += 4) {
    int e0 = col[p].y, e1 = col[p + 1].y, e2 = col[p + 2].y, e3 = col[p + 3].y;
    float4 v0 = ((const float4*)(edge_attr + (size_t)e0 * DIM))[lane];
    float4 v1 = ((const float4*)(edge_attr + (size_t)e1 * DIM))[lane];
    float4 v2 = ((const float4*)(edge_attr + (size_t)e2 * DIM))[lane];
    float4 v3 = ((const float4*)(edge_attr + (size_t)e3 * DIM))[lane];
    ax += v0.x + v1.x + v2.x + v3.x;
    ay += v0.y + v1.y + v2.y + v3.y;
    az += v0.z + v1.z + v2.z + v3.z;
    aw += v0.w + v1.w + v2.w + v3.w;
  }
  for (; p < e; p++) {
    int e0 = col[p].y;
    float4 v0 = ((const float4*)(edge_attr + (size_t)e0 * DIM))[lane];
    ax += v0.x; ay += v0.y; az += v0.z; aw += v0.w;
  }
  float r = 1.0f / (float)max(e - b, 1);
  if (lane == 0) rdeg[i] = r;
  uint2 o;
  o.x = f2bf(ax * r) | (f2bf(ay * r) << 16);
  o.y = f2bf(az * r) | (f2bf(aw * r) << 16);
  ((uint2*)(ean + (size_t)i * DIM))[lane] = o;
}

// ------- layer 0: h = relu(ean @ We0 + s_i * v0 + b0),  s_i = 1+[deg>0] ----
// A-fragments read DIRECTLY from global ean (L2/L3-resident): no sA staging.
__global__ __launch_bounds__(256) void k_gemm0(
    const unsigned short* __restrict__ ean, const unsigned short* __restrict__ W1,
    const float* __restrict__ v0, const float* __restrict__ bias,
    const int* __restrict__ deg, unsigned short* __restrict__ hout) {
  __shared__ unsigned short sW[128][72];   // W chunk (64-k at a time)
  int tid = threadIdx.x;
  int wave = tid >> 6, lane = tid & 63;
  int quad = lane >> 4, l16 = lane & 15;
  int row0 = blockIdx.x * 64;
  int row_a = row0 + wave * 16 + l16;      // A-operand row for this lane
  floatx4 acc[8];
  #pragma unroll
  for (int ci = 0; ci < 8; ci++) acc[ci] = (floatx4){0.f, 0.f, 0.f, 0.f};

  for (int kc = 0; kc < 128; kc += 64) {
    __syncthreads();
    #pragma unroll
    for (int q = 0; q < 4; q++) {
      int s = tid + 256 * q;
      int r = s >> 3, seg = s & 7;
      *(uint4*)(&sW[r][seg * 8]) =
          *(const uint4*)(W1 + (size_t)r * DIM + kc + seg * 8);
    }
    __syncthreads();
    #pragma unroll
    for (int ks = 0; ks < 64; ks += 32) {
      short8 a = {0, 0, 0, 0, 0, 0, 0, 0};
      if (row_a < N_NODES)
        a = *(const short8*)(ean + (size_t)row_a * DIM + kc + ks + quad * 8);
      #pragma unroll
      for (int ci = 0; ci < 8; ci++) {
        short8 b = *(const short8*)(&sW[ci * 16 + l16][ks + quad * 8]);
        acc[ci] = __builtin_amdgcn_mfma_f32_16x16x32_bf16(a, b, acc[ci], 0, 0, 0);
      }
    }
  }
  #pragma unroll
  for (int ci = 0; ci < 8; ci++) {
    int col = ci * 16 + l16;
    float bv = bias[col];
    float vv = v0[col];
    #pragma unroll
    for (int r = 0; r < 4; r++) {
      int row = row0 + wave * 16 + quad * 4 + r;
      if (row < N_NODES) {
        float s = (deg[row] > 0) ? 2.f : 1.f;
        float v = acc[ci][r] + bv + s * vv;
        v = fmaxf(v, 0.f);                       // layer 0 always has relu
        hout[(size_t)row * DIM + col] = (unsigned short)f2bf(v);
      }
    }
  }
}

// ------- layers 1..4 fused:  h' = maybe_relu(u @ W0 + ean @ W1 + b)  -------
// u = hin + (A hin)/max(deg,1) gathered BLOCK-LOCALLY into LDS.
// ean A-fragments read directly from global (no sE): LDS 35840B -> 4 blk/CU.
#define ACC8(v) { a0 += bflo(v.x); a1 += bfhi(v.x); a2 += bflo(v.y); a3 += bfhi(v.y); \
                  a4 += bflo(v.z); a5 += bfhi(v.z); a6 += bflo(v.w); a7 += bfhi(v.w); }

__global__ __launch_bounds__(256) void k_layer(
    const int* __restrict__ row_ptr, const int2* __restrict__ col,
    const unsigned short* __restrict__ hin, const float* __restrict__ rdeg,
    const unsigned short* __restrict__ ean,
    const unsigned short* __restrict__ W0, const unsigned short* __restrict__ W1,
    const float* __restrict__ bias, unsigned short* __restrict__ hout, int relu) {
  __shared__ unsigned short sU[64][136];   // gathered u rows, full K=128 (+8 pad)
  __shared__ unsigned short sW[128][72];   // W chunk staging (64-k at a time)
  int tid = threadIdx.x;
  int row0 = blockIdx.x * 64;

  // ---- gather u rows into sU: 16 lane-groups, 4 nodes each, 4-way MLP unroll
  {
    int g = tid >> 4, glane = tid & 15;
    for (int n = 0; n < 4; n++) {
      int r = g + n * 16;
      int i = row0 + r;
      if (i < N_NODES) {
        int b = row_ptr[i], e = row_ptr[i + 1];
        float a0 = 0.f, a1 = 0.f, a2 = 0.f, a3 = 0.f,
              a4 = 0.f, a5 = 0.f, a6 = 0.f, a7 = 0.f;
        int p = b;
        for (; p + 4 <= e; p += 4) {
          int j0 = col[p].x, j1 = col[p + 1].x, j2 = col[p + 2].x, j3 = col[p + 3].x;
          uint4 w0 = *(const uint4*)(hin + (size_t)j0 * DIM + glane * 8);
          uint4 w1 = *(const uint4*)(hin + (size_t)j1 * DIM + glane * 8);
          uint4 w2 = *(const uint4*)(hin + (size_t)j2 * DIM + glane * 8);
          uint4 w3 = *(const uint4*)(hin + (size_t)j3 * DIM + glane * 8);
          ACC8(w0); ACC8(w1); ACC8(w2); ACC8(w3);
        }
        for (; p < e; p++) {
          int j0 = col[p].x;
          uint4 w0 = *(const uint4*)(hin + (size_t)j0 * DIM + glane * 8);
          ACC8(w0);
        }
        float rr = rdeg[i];
        uint4 hv = *(const uint4*)(hin + (size_t)i * DIM + glane * 8);
        uint4 o;
        o.x = f2bf(bflo(hv.x) + a0 * rr) | (f2bf(bfhi(hv.x) + a1 * rr) << 16);
        o.y = f2bf(bflo(hv.y) + a2 * rr) | (f2bf(bfhi(hv.y) + a3 * rr) << 16);
        o.z = f2bf(bflo(hv.z) + a4 * rr) | (f2bf(bfhi(hv.z) + a5 * rr) << 16);
        o.w = f2bf(bflo(hv.w) + a6 * rr) | (f2bf(bfhi(hv.w) + a7 * rr) << 16);
        *(uint4*)(&sU[r][glane * 8]) = o;
      } else {
        *(uint4*)(&sU[r][glane * 8]) = make_uint4(0u, 0u, 0u, 0u);
      }
    }
  }

  // ---- GEMM: acc = sU @ W0 + ean(global) @ W1
  int wave = tid >> 6, lane = tid & 63;
  int quad = lane >> 4, l16 = lane & 15;
  int row_a = row0 + wave * 16 + l16;      // A-operand row for this lane
  floatx4 acc[8];
  #pragma unroll
  for (int ci = 0; ci < 8; ci++) acc[ci] = (floatx4){0.f, 0.f, 0.f, 0.f};

  for (int m = 0; m < 2; m++) {
    const unsigned short* W = m ? W1 : W0;
    for (int kc = 0; kc < 128; kc += 64) {
      __syncthreads();   // orders sU writes (first pass) and sW reuse
      #pragma unroll
      for (int q = 0; q < 4; q++) {
        int s = tid + 256 * q;
        int r = s >> 3, seg = s & 7;
        *(uint4*)(&sW[r][seg * 8]) =
            *(const uint4*)(W + (size_t)r * DIM + kc + seg * 8);
      }
      __syncthreads();
      #pragma unroll
      for (int ks = 0; ks < 64; ks += 32) {
        short8 a;
        if (m == 0) {
          a = *(const short8*)(&sU[wave * 16 + l16][kc + ks + quad * 8]);
        } else {
          a = (short8){0, 0, 0, 0, 0, 0, 0, 0};
          if (row_a < N_NODES)
            a = *(const short8*)(ean + (size_t)row_a * DIM + kc + ks + quad * 8);
        }
        #pragma unroll
        for (int ci = 0; ci < 8; ci++) {
          short8 b = *(const short8*)(&sW[ci * 16 + l16][ks + quad * 8]);
          acc[ci] = __builtin_amdgcn_mfma_f32_16x16x32_bf16(a, b, acc[ci], 0, 0, 0);
        }
      }
    }
  }
  // epilogue: row = row0 + wave*16 + quad*4 + r ; col = ci*16 + l16
  #pragma unroll
  for (int ci = 0; ci < 8; ci++) {
    int col_ = ci * 16 + l16;
    float bv = bias[col_];
    #pragma unroll
    for (int r = 0; r < 4; r++) {
      int row = row0 + wave * 16 + quad * 4 + r;
      if (row < N_NODES) {
        float v = acc[ci][r] + bv;
        if (relu) v = fmaxf(v, 0.f);
        hout[(size_t)row * DIM + col_] = (unsigned short)f2bf(v);
      }
    }
  }
}

// ---------------- mean-pool per graph (batch sorted: run-length) -----------
__global__ void k_pool(const unsigned short* __restrict__ h, const int* __restrict__ batch,
                       float* __restrict__ pool, float* __restrict__ cnt) {
  int t = threadIdx.x;                 // column 0..127
  int i0 = blockIdx.x * 128;
  int iend = min(i0 + 128, N_NODES);
  float acc = 0.f;
  int cur = -1, run = 0;
  for (int i = i0; i < iend; i++) {
    int g = batch[i];
    if (g != cur) {
      if (cur >= 0) {
        atomicAdd(&pool[(size_t)cur * DIM + t], acc);
        if (t == 0) atomicAdd(&cnt[cur], (float)run);
      }
      acc = 0.f; run = 0; cur = g;
    }
    acc += __uint_as_float(((unsigned)h[(size_t)i * DIM + t]) << 16);
    run++;
  }
  if (cur >= 0) {
    atomicAdd(&pool[(size_t)cur * DIM + t], acc);
    if (t == 0) atomicAdd(&cnt[cur], (float)run);
  }
}

// ---------------- out = (pool/cnt) @ Wp + bp -------------------------------
__global__ void k_out(const float* __restrict__ pool, const float* __restrict__ cnt,
                      const float* __restrict__ Wp, const float* __restrict__ bp,
                      float* __restrict__ out) {
  __shared__ float sp[DIM];
  int g = blockIdx.x, t = threadIdx.x;
  sp[t] = pool[(size_t)g * DIM + t];
  __syncthreads();
  float r = 1.0f / fmaxf(cnt[g], 1.0f);
  float acc = 0.f;
  for (int k = 0; k < DIM; k++) acc += sp[k] * Wp[(size_t)k * N_CLASSES + t];
  out[(size_t)g * N_CLASSES + t] = acc * r + bp[t];
}

extern "C" void kernel_launch(void* const* d_in, const int* in_sizes, int n_in,
                              void* d_out, int out_size, void* d_ws, size_t ws_size,
                              hipStream_t stream) {
  (void)in_sizes; (void)n_in; (void)out_size; (void)ws_size;
  const int*   x          = (const int*)d_in[0];
  const int*   edge_index = (const int*)d_in[1];
  const float* edge_attr  = (const float*)d_in[2];
  const int*   batch      = (const int*)d_in[3];
  const float* node_emb   = (const float*)d_in[4];
  const float* Ws         = (const float*)d_in[5];
  const float* bsin       = (const float*)d_in[6];
  const float* Wes        = (const float*)d_in[7];
  const float* Wp         = (const float*)d_in[8];
  const float* bp         = (const float*)d_in[9];
  (void)x;
  float* out = (float*)d_out;
  const int* src = edge_index;
  const int* dst = edge_index + N_EDGES;

  char* p = (char*)d_ws;
  auto alloc = [&](size_t bytes) {
    void* q = (void*)p;
    p += (bytes + 255) & ~(size_t)255;
    return q;
  };
  unsigned short* h    = (unsigned short*)alloc((size_t)N_NODES * DIM * 2);
  unsigned short* h2   = (unsigned short*)alloc((size_t)N_NODES * DIM * 2);
  unsigned short* ean  = (unsigned short*)alloc((size_t)N_NODES * DIM * 2);
  unsigned short* Wt_s = (unsigned short*)alloc((size_t)N_LAYERS * DIM * DIM * 2);
  unsigned short* Wt_e = (unsigned short*)alloc((size_t)N_LAYERS * DIM * DIM * 2);
  int*   deg     = (int*)  alloc((size_t)N_NODES * 4);
  float* rdeg    = (float*)alloc((size_t)N_NODES * 4);
  int*   row_ptr = (int*)  alloc((size_t)(N_NODES + 64) * 4);
  int*   fill    = (int*)  alloc((size_t)N_NODES * 4);
  int2*  col     = (int2*) alloc((size_t)N_EDGES * 8);
  float* pool    = (float*)alloc((size_t)N_GRAPHS * DIM * 4);
  float* cnt     = (float*)alloc((size_t)N_GRAPHS * 4);
  int*   bsum    = (int*)  alloc(256 * 4);
  float* v0      = (float*)alloc(DIM * 4);

  k_zero<<<256, 256, 0, stream>>>(deg, fill, pool, cnt);
  k_deg<<<(N_EDGES + 255) / 256, 256, 0, stream>>>(dst, deg);
  k_scan1<<<NB_SCAN, 256, 0, stream>>>(deg, bsum);
  k_scan2<<<1, 256, 0, stream>>>(bsum);
  k_scan3<<<NB_SCAN, 256, 0, stream>>>(deg, bsum, row_ptr);
  k_fill<<<(N_EDGES + 255) / 256, 256, 0, stream>>>(src, dst, row_ptr, fill, col);
  k_wconv<<<(2 * N_LAYERS * DIM * DIM) / 256, 256, 0, stream>>>(Ws, Wes, Wt_s, Wt_e);
  k_v0<<<1, DIM, 0, stream>>>(node_emb, Ws, v0);
  k_ean_init<<<(N_NODES + 7) / 8, 256, 0, stream>>>(row_ptr, col, edge_attr, ean, rdeg);

  // layer 0: rank-1 collapse (h0 rows all == emb); writes h
  k_gemm0<<<(N_NODES + 63) / 64, 256, 0, stream>>>(
      ean, Wt_e, v0, bsin, deg, h);
  // layers 1..4: fused block-local gather + dual GEMM, ping-pong h <-> h2
  const unsigned short* hin = h;
  unsigned short* hout = h2;
  for (int l = 1; l < N_LAYERS; l++) {
    k_layer<<<(N_NODES + 63) / 64, 256, 0, stream>>>(
        row_ptr, col, hin, rdeg, ean,
        Wt_s + (size_t)l * DIM * DIM, Wt_e + (size_t)l * DIM * DIM,
        bsin + (size_t)l * DIM, hout, (l < N_LAYERS - 1) ? 1 : 0);
    const unsigned short* tmp = hout; hout = (unsigned short*)hin; hin = tmp;
  }
  // after 4 layers (even number of swaps) the final result is in h
  k_pool<<<(N_NODES + 127) / 128, 128, 0, stream>>>(h, batch, pool, cnt);
  k_out<<<N_GRAPHS, N_CLASSES, 0, stream>>>(pool, cnt, Wp, bp, out);
}